// Round 1
// baseline (217.106 us; speedup 1.0000x reference)
//
#include <hip/hip_runtime.h>

#define B_   2
#define H_   16
#define S_   2048
#define D_   64
#define BQ   64     // q rows per block (16 per wave)
#define BK   32     // k cols per tile
#define NW   4      // waves per block
#define SCALE 0.125f        // 1/sqrt(64)
#define L2E  1.44269504088896341f

typedef _Float16 f16x8 __attribute__((ext_vector_type(8)));
typedef float    f32x4 __attribute__((ext_vector_type(4)));

__global__ __launch_bounds__(256) void attn_fwd_f16(
    const float* __restrict__ Q, const float* __restrict__ K,
    const float* __restrict__ V, float* __restrict__ O)
{
    // LDS: K tile (row-major, padded), V tile (TRANSPOSED [d][k], padded),
    // per-wave P buffer for C-layout -> A-fragment relayout.
    __shared__ _Float16 Kt[BK][D_ + 8];        // 144B row stride (16B aligned)
    __shared__ _Float16 Vt[D_][BK + 8];        // 80B row stride  (16B aligned)
    __shared__ _Float16 Pl[NW][16][BK + 8];    // 80B row stride

    const int tid  = threadIdx.x;
    const int lane = tid & 63;
    const int w    = tid >> 6;       // wave id 0..3
    const int g    = lane >> 4;      // 4-group id 0..3
    const int l15  = lane & 15;

    const int qt    = blockIdx.x;    // 0..S/BQ-1
    const int bh    = blockIdx.y;    // 0..B*H-1
    const int qbase = qt * BQ;

    const size_t headoff = (size_t)bh * S_ * D_;
    const float* Qh = Q + headoff;
    const float* Kh = K + headoff;
    const float* Vh = V + headoff;
    float*       Oh = O + headoff;

    // ---- hoist Q fragments (A operand): row = qbase + w*16 + l15, k = kc*32 + g*8 + j
    f16x8 aq[2];
    {
        const float* qrow = Qh + (size_t)(qbase + w * 16 + l15) * D_;
        for (int kc = 0; kc < 2; ++kc) {
            const float4* p = (const float4*)(qrow + kc * 32 + g * 8);
            float4 x0 = p[0], x1 = p[1];
            f16x8 h;
            h[0] = (_Float16)x0.x; h[1] = (_Float16)x0.y;
            h[2] = (_Float16)x0.z; h[3] = (_Float16)x0.w;
            h[4] = (_Float16)x1.x; h[5] = (_Float16)x1.y;
            h[6] = (_Float16)x1.z; h[7] = (_Float16)x1.w;
            aq[kc] = h;
        }
    }

    // staging assignment: each thread loads 8 consecutive floats of the 32x64 tile
    const int sr = tid >> 3;          // tile row 0..31
    const int sc = (tid & 7) * 8;     // tile col 0..56

    f32x4 accO[4];
    for (int i = 0; i < 4; ++i) accO[i] = (f32x4){0.f, 0.f, 0.f, 0.f};
    float m_r[4], l_r[4];
    for (int r = 0; r < 4; ++r) { m_r[r] = -1e30f; l_r[r] = 0.f; }

    const int ntiles = (qbase + BQ) / BK;   // causal: only tiles up to the diagonal

    for (int kt = 0; kt < ntiles; ++kt) {
        // ---- stage K (row-major) and V (transposed) fp32 -> f16 into LDS
        {
            const float* krow = Kh + (size_t)(kt * BK + sr) * D_ + sc;
            float4 a = ((const float4*)krow)[0];
            float4 b = ((const float4*)krow)[1];
            f16x8 h;
            h[0] = (_Float16)a.x; h[1] = (_Float16)a.y;
            h[2] = (_Float16)a.z; h[3] = (_Float16)a.w;
            h[4] = (_Float16)b.x; h[5] = (_Float16)b.y;
            h[6] = (_Float16)b.z; h[7] = (_Float16)b.w;
            *(f16x8*)&Kt[sr][sc] = h;

            const float* vrow = Vh + (size_t)(kt * BK + sr) * D_ + sc;
            float4 c = ((const float4*)vrow)[0];
            float4 d = ((const float4*)vrow)[1];
            Vt[sc + 0][sr] = (_Float16)c.x;
            Vt[sc + 1][sr] = (_Float16)c.y;
            Vt[sc + 2][sr] = (_Float16)c.z;
            Vt[sc + 3][sr] = (_Float16)c.w;
            Vt[sc + 4][sr] = (_Float16)d.x;
            Vt[sc + 5][sr] = (_Float16)d.y;
            Vt[sc + 6][sr] = (_Float16)d.z;
            Vt[sc + 7][sr] = (_Float16)d.w;
        }
        __syncthreads();

        // ---- QK^T : scores tile 16 x 32 per wave (two 16x16 col subtiles)
        f32x4 accS[2];
        accS[0] = (f32x4){0.f, 0.f, 0.f, 0.f};
        accS[1] = (f32x4){0.f, 0.f, 0.f, 0.f};
        for (int sub = 0; sub < 2; ++sub) {
            for (int kc = 0; kc < 2; ++kc) {
                f16x8 bk = *(const f16x8*)&Kt[sub * 16 + l15][kc * 32 + g * 8];
                accS[sub] = __builtin_amdgcn_mfma_f32_16x16x32_f16(aq[kc], bk, accS[sub], 0, 0, 0);
            }
        }

        // ---- online softmax (fp32). C layout: col = l15, row = g*4 + r.
        const int c0 = kt * BK + l15;
        const int c1 = c0 + 16;
        float alpha[4];
        for (int r = 0; r < 4; ++r) {
            const int qrow = qbase + w * 16 + g * 4 + r;
            float s0 = accS[0][r] * SCALE;
            float s1 = accS[1][r] * SCALE;
            if (c0 > qrow) s0 = -1e30f;
            if (c1 > qrow) s1 = -1e30f;

            float mx = fmaxf(s0, s1);
            mx = fmaxf(mx, __shfl_xor(mx, 1));
            mx = fmaxf(mx, __shfl_xor(mx, 2));
            mx = fmaxf(mx, __shfl_xor(mx, 4));
            mx = fmaxf(mx, __shfl_xor(mx, 8));

            const float mnew = fmaxf(m_r[r], mx);
            const float al   = __builtin_amdgcn_exp2f((m_r[r] - mnew) * L2E);
            const float p0   = __builtin_amdgcn_exp2f((s0 - mnew) * L2E);
            const float p1   = __builtin_amdgcn_exp2f((s1 - mnew) * L2E);

            float rs = p0 + p1;
            rs += __shfl_xor(rs, 1);
            rs += __shfl_xor(rs, 2);
            rs += __shfl_xor(rs, 4);
            rs += __shfl_xor(rs, 8);

            l_r[r]   = l_r[r] * al + rs;
            m_r[r]   = mnew;
            alpha[r] = al;

            Pl[w][g * 4 + r][l15]      = (_Float16)p0;
            Pl[w][g * 4 + r][16 + l15] = (_Float16)p1;
        }

        // rescale running O by alpha (per-row; O shares the C row mapping)
        for (int dt = 0; dt < 4; ++dt)
            for (int r = 0; r < 4; ++r)
                accO[dt][r] *= alpha[r];

        // wave-local LDS write->read fence for Pl (no block barrier needed)
        asm volatile("s_waitcnt lgkmcnt(0)" ::: "memory");

        // ---- PV : A = P (relayout via LDS), B = V^T tile (contiguous 16B reads)
        f16x8 ap = *(const f16x8*)&Pl[w][l15][g * 8];
        for (int dt = 0; dt < 4; ++dt) {
            f16x8 bv = *(const f16x8*)&Vt[dt * 16 + l15][g * 8];
            accO[dt] = __builtin_amdgcn_mfma_f32_16x16x32_f16(ap, bv, accO[dt], 0, 0, 0);
        }
        __syncthreads();   // protect Kt/Vt before next stage overwrites
    }

    // ---- epilogue: normalize and store fp32
    for (int dt = 0; dt < 4; ++dt) {
        for (int r = 0; r < 4; ++r) {
            const float o = accO[dt][r] / l_r[r];
            Oh[(size_t)(qbase + w * 16 + g * 4 + r) * D_ + dt * 16 + l15] = o;
        }
    }
}

extern "C" void kernel_launch(void* const* d_in, const int* in_sizes, int n_in,
                              void* d_out, int out_size, void* d_ws, size_t ws_size,
                              hipStream_t stream) {
    const float* q = (const float*)d_in[0];
    const float* k = (const float*)d_in[1];
    const float* v = (const float*)d_in[2];
    // d_in[3] is the causal mask — never read; causality is computed in-kernel.
    float* o = (float*)d_out;

    dim3 grid(S_ / BQ, B_ * H_);
    attn_fwd_f16<<<grid, 256, 0, stream>>>(q, k, v, o);
}

// Round 2
// 90.415 us; speedup vs baseline: 2.4012x; 2.4012x over previous
//
#include <hip/hip_runtime.h>

#define B_   2
#define H_   16
#define S_   2048
#define D_   64
#define BQ   64
#define BK   64
#define NW   4
// fold 1/sqrt(64) * log2(e) into Q so softmax works in exp2 domain
#define QSCALE 0.18033688011112042f

typedef _Float16 f16x8 __attribute__((ext_vector_type(8)));
typedef _Float16 f16x4 __attribute__((ext_vector_type(4)));
typedef float    f32x4 __attribute__((ext_vector_type(4)));

typedef const unsigned int __attribute__((address_space(1))) gu32;
typedef unsigned int       __attribute__((address_space(3))) lu32;

#define KBYTES_PER_HEAD (S_ * 128)              // 256 KB of f16 per head per tensor
#define WS_V_OFF ((size_t)B_ * H_ * KBYTES_PER_HEAD)    // 8 MB
#define WS_NEED  (2 * WS_V_OFF)                          // 16.8 MB

// ---------------- prepass: K fp32 -> f16, tile-chunked, pre-swizzled LDS image
// image of 64-row tile: element (row, d) at byte  row*128 + (((d>>3) ^ (row&7))<<4) + (d&7)*2
__global__ __launch_bounds__(256) void prep_k(const float* __restrict__ K, char* __restrict__ ws)
{
    const int gidx = blockIdx.x * 256 + threadIdx.x;   // B*H*S*8 granule tasks
    const int gcol = gidx & 7;
    const int srow = gidx >> 3;                        // bh*S + s
    const float4* src = (const float4*)(K + (size_t)srow * D_ + gcol * 8);
    float4 a = src[0], b = src[1];
    f16x8 h;
    h[0] = (_Float16)a.x; h[1] = (_Float16)a.y; h[2] = (_Float16)a.z; h[3] = (_Float16)a.w;
    h[4] = (_Float16)b.x; h[5] = (_Float16)b.y; h[6] = (_Float16)b.z; h[7] = (_Float16)b.w;
    const int s  = srow & (S_ - 1);
    const int bh = srow >> 11;
    size_t off = (size_t)bh * KBYTES_PER_HEAD + (size_t)(s >> 6) * 8192
               + (s & 63) * 128 + ((gcol ^ (s & 7)) << 4);
    *(f16x8*)(ws + off) = h;
}

// ---------------- prepass: V fp32 -> f16 transposed [d][k] per 64-k-tile, same swizzle
__global__ __launch_bounds__(256) void prep_v(const float* __restrict__ V, char* __restrict__ ws)
{
    __shared__ _Float16 Vl[64][72];
    const int tile = blockIdx.x;           // bh*32 + t
    const int bh = tile >> 5, t = tile & 31;
    const float* vb = V + ((size_t)bh * S_ + t * 64) * D_;
    const int tid = threadIdx.x;
    #pragma unroll
    for (int it = 0; it < 2; ++it) {
        const int row = (tid >> 3) + it * 32;
        const int c8  = (tid & 7) * 8;
        const float4* p = (const float4*)(vb + row * D_ + c8);
        float4 a = p[0], b = p[1];
        f16x8 h;
        h[0] = (_Float16)a.x; h[1] = (_Float16)a.y; h[2] = (_Float16)a.z; h[3] = (_Float16)a.w;
        h[4] = (_Float16)b.x; h[5] = (_Float16)b.y; h[6] = (_Float16)b.z; h[7] = (_Float16)b.w;
        *(f16x8*)&Vl[row][c8] = h;
    }
    __syncthreads();
    char* out = ws + WS_V_OFF + (size_t)bh * KBYTES_PER_HEAD + t * 8192;
    #pragma unroll
    for (int it = 0; it < 2; ++it) {
        const int task = tid + it * 256;
        const int d = task >> 3, kg = task & 7;
        f16x8 h;
        #pragma unroll
        for (int j = 0; j < 8; ++j) h[j] = Vl[kg * 8 + j][d];
        *(f16x8*)(out + d * 128 + ((kg ^ (d & 7)) << 4)) = h;
    }
}

// ---------------- main attention kernel
template<bool MASK>
__device__ __forceinline__ void compute_tile(
    const _Float16* __restrict__ SMb, _Float16 (*__restrict__ Plw)[72],
    const f16x8 aq[2], f32x4 accO[4], float& m_r, float& l_r,
    int w, int g, int l15, int sx)
{
    const _Float16* Kb = SMb;
    const _Float16* Vb = SMb + 4096;

    // QK^T swapped: C[k-sub = g*4+r][q = l15], A = K rows, B = Q
    f32x4 accS[4];
    #pragma unroll
    for (int s = 0; s < 4; ++s) accS[s] = (f32x4){0.f, 0.f, 0.f, 0.f};
    #pragma unroll
    for (int sub = 0; sub < 4; ++sub) {
        if (MASK && sub > w) continue;            // wave-uniform: fully-masked sub-tile
        #pragma unroll
        for (int kc = 0; kc < 2; ++kc) {
            f16x8 ak = *(const f16x8*)(Kb + ((sub * 16 + l15) * 64 + (((kc * 4 + g) ^ sx) << 3)));
            accS[sub] = __builtin_amdgcn_mfma_f32_16x16x32_f16(ak, aq[kc], accS[sub], 0, 0, 0);
        }
    }

    // online softmax in log2 domain; q-row = l15 is lane-local
    float ps[4][4];
    float mx = -1e30f;
    #pragma unroll
    for (int sub = 0; sub < 4; ++sub) {
        const bool dead = MASK && sub > w;
        #pragma unroll
        for (int r = 0; r < 4; ++r) {
            float s = dead ? -1e30f : accS[sub][r];
            if (MASK && sub == w) { if (g * 4 + r > l15) s = -1e30f; }
            ps[sub][r] = s;
            mx = fmaxf(mx, s);
        }
    }
    mx = fmaxf(mx, __shfl_xor(mx, 16));
    mx = fmaxf(mx, __shfl_xor(mx, 32));
    const float mnew  = fmaxf(m_r, mx);
    const float alpha = __builtin_amdgcn_exp2f(m_r - mnew);
    float rs = 0.f;
    #pragma unroll
    for (int sub = 0; sub < 4; ++sub)
        #pragma unroll
        for (int r = 0; r < 4; ++r) {
            const float p = __builtin_amdgcn_exp2f(ps[sub][r] - mnew);
            ps[sub][r] = p;
            rs += p;
        }
    rs += __shfl_xor(rs, 16);
    rs += __shfl_xor(rs, 32);
    l_r = l_r * alpha + rs;
    m_r = mnew;

    // P -> LDS relayout (wave-local): row q=l15, col k
    #pragma unroll
    for (int sub = 0; sub < 4; ++sub) {
        f16x4 q4;
        q4[0] = (_Float16)ps[sub][0]; q4[1] = (_Float16)ps[sub][1];
        q4[2] = (_Float16)ps[sub][2]; q4[3] = (_Float16)ps[sub][3];
        *(f16x4*)&Plw[l15][sub * 16 + g * 4] = q4;
    }

    #pragma unroll
    for (int d = 0; d < 4; ++d)
        #pragma unroll
        for (int r = 0; r < 4; ++r) accO[d][r] *= alpha;   // alpha lane-uniform (q=l15)

    asm volatile("s_waitcnt lgkmcnt(0)" ::: "memory");
    __builtin_amdgcn_sched_barrier(0);

    f16x8 pb[2];
    pb[0] = *(const f16x8*)&Plw[l15][g * 8];
    pb[1] = *(const f16x8*)&Plw[l15][32 + g * 8];

    // PV swapped: A = V^T rows (d), B = P^T cols (q) -> accO[dsub][r]: d = dsub*16+g*4+r, q = l15
    #pragma unroll
    for (int d = 0; d < 4; ++d)
        #pragma unroll
        for (int kc = 0; kc < 2; ++kc) {
            f16x8 av = *(const f16x8*)(Vb + ((d * 16 + l15) * 64 + (((kc * 4 + g) ^ sx) << 3)));
            accO[d] = __builtin_amdgcn_mfma_f32_16x16x32_f16(av, pb[kc], accO[d], 0, 0, 0);
        }
}

__global__ __launch_bounds__(256, 3) void attn_main(
    const float* __restrict__ Q, const char* __restrict__ ws, float* __restrict__ O)
{
    __shared__ _Float16 SM[2][8192];        // [buf][ K tile: 0..4095 | V tile: 4096..8191 ]
    __shared__ _Float16 Pl[NW][16][72];

    const int tid  = threadIdx.x;
    const int lane = tid & 63;
    const int w    = tid >> 6;
    const int g    = lane >> 4;
    const int l15  = lane & 15;
    const int sx   = l15 & 7;

    const int qt    = blockIdx.x;
    const int bh    = blockIdx.y;
    const int qbase = qt * BQ;

    const char* kbase = ws + (size_t)bh * KBYTES_PER_HEAD;
    const char* vbase = ws + WS_V_OFF + (size_t)bh * KBYTES_PER_HEAD;

    // hoist Q fragments, pre-scaled into log2 domain
    f16x8 aq[2];
    {
        const float* qrow = Q + ((size_t)bh * S_ + qbase + w * 16 + l15) * D_;
        #pragma unroll
        for (int kc = 0; kc < 2; ++kc) {
            const float4* p = (const float4*)(qrow + kc * 32 + g * 8);
            float4 x0 = p[0], x1 = p[1];
            f16x8 h;
            h[0] = (_Float16)(x0.x * QSCALE); h[1] = (_Float16)(x0.y * QSCALE);
            h[2] = (_Float16)(x0.z * QSCALE); h[3] = (_Float16)(x0.w * QSCALE);
            h[4] = (_Float16)(x1.x * QSCALE); h[5] = (_Float16)(x1.y * QSCALE);
            h[6] = (_Float16)(x1.z * QSCALE); h[7] = (_Float16)(x1.w * QSCALE);
            aq[kc] = h;
        }
    }

    f32x4 accO[4];
    #pragma unroll
    for (int i = 0; i < 4; ++i) accO[i] = (f32x4){0.f, 0.f, 0.f, 0.f};
    float m_r = -1e30f, l_r = 0.f;

    const int nt = qt + 1;

    // stage tile t into buf: 16 x 1KB chunks across 4 waves, linear LDS dest
    auto STAGE = [&](int t, int buf) {
        #pragma unroll
        for (int i = 0; i < 4; ++i) {
            const int c = w * 4 + i;
            const char* src = (c < 8 ? kbase + (size_t)t * 8192 + c * 1024
                                     : vbase + (size_t)t * 8192 + (c - 8) * 1024) + lane * 16;
            _Float16* dst = &SM[buf][c * 512];
            __builtin_amdgcn_global_load_lds((gu32*)src, (lu32*)dst, 16, 0, 0);
        }
    };

    STAGE(0, 0);
    for (int t = 0; t < nt - 1; ++t) {
        STAGE(t + 1, (t + 1) & 1);                       // prefetch stays in flight
        asm volatile("s_waitcnt vmcnt(4)" ::: "memory"); // current tile's 4 loads done
        __builtin_amdgcn_s_barrier();
        compute_tile<false>(&SM[t & 1][0], Pl[w], aq, accO, m_r, l_r, w, g, l15, sx);
        __builtin_amdgcn_s_barrier();                    // all waves done with buf before re-stage
    }
    asm volatile("s_waitcnt vmcnt(0)" ::: "memory");
    __builtin_amdgcn_s_barrier();
    compute_tile<true>(&SM[(nt - 1) & 1][0], Pl[w], aq, accO, m_r, l_r, w, g, l15, sx);

    // epilogue: O[q][d], float4 stores
    const float inv = 1.0f / l_r;
    float* orow = O + ((size_t)bh * S_ + qbase + w * 16 + l15) * D_;
    #pragma unroll
    for (int d = 0; d < 4; ++d) {
        f32x4 o = accO[d] * inv;
        *(f32x4*)&orow[d * 16 + g * 4] = o;
    }
}

extern "C" void kernel_launch(void* const* d_in, const int* in_sizes, int n_in,
                              void* d_out, int out_size, void* d_ws, size_t ws_size,
                              hipStream_t stream) {
    const float* q = (const float*)d_in[0];
    const float* k = (const float*)d_in[1];
    const float* v = (const float*)d_in[2];
    // d_in[3] (mask) intentionally never read — causality computed in-kernel
    float* o = (float*)d_out;
    char* ws = (char*)d_ws;

    if (ws_size < WS_NEED) return;   // evidence: ws is ~2 GiB; guard only

    prep_k<<<(B_ * H_ * S_ * 8) / 256, 256, 0, stream>>>(k, ws);
    prep_v<<<B_ * H_ * (S_ / 64), 256, 0, stream>>>(v, ws);
    dim3 grid(S_ / BQ, B_ * H_);
    attn_main<<<grid, 256, 0, stream>>>(q, ws, o);
}

// Round 3
// 57.188 us; speedup vs baseline: 3.7964x; 1.5810x over previous
//
#include <hip/hip_runtime.h>

#define B_   2
#define H_   16
#define S_   2048
#define D_   64
#define BQ   128    // q rows per block (16 per wave, 8 waves)
#define BK   64
#define NW   8
// fold 1/sqrt(64) * log2(e) into Q so softmax works in exp2 domain
#define QSCALE 0.18033688011112042f

typedef _Float16 f16x8 __attribute__((ext_vector_type(8)));
typedef _Float16 f16x4 __attribute__((ext_vector_type(4)));
typedef float    f32x4 __attribute__((ext_vector_type(4)));

typedef const unsigned int __attribute__((address_space(1))) gu32;
typedef unsigned int       __attribute__((address_space(3))) lu32;

#define KBYTES_PER_HEAD (S_ * 128)                       // 256 KB f16 per head per tensor
#define WS_V_OFF ((size_t)B_ * H_ * KBYTES_PER_HEAD)     // 8.4 MB
#define WS_NEED  (2 * WS_V_OFF)

// ---------------- fused prepass: K -> swizzled f16 tiles, V -> transposed swizzled f16 tiles
// K tile image: element (row,d) at byte  row*128 + (((d>>3) ^ (row&7))<<4) + (d&7)*2
// V tile image: element (d,k)  at byte  d*128   + (((k>>3) ^ (d&7))<<4)   + (k&7)*2
__global__ __launch_bounds__(256) void prep_kv(const float* __restrict__ K,
                                               const float* __restrict__ V,
                                               char* __restrict__ ws)
{
    if (blockIdx.x < (B_ * H_ * S_ * 8) / 256) {
        const int gidx = blockIdx.x * 256 + threadIdx.x;
        const int gcol = gidx & 7;
        const int srow = gidx >> 3;                      // bh*S + s
        const float4* src = (const float4*)(K + (size_t)srow * D_ + gcol * 8);
        float4 a = src[0], b = src[1];
        f16x8 h;
        h[0] = (_Float16)a.x; h[1] = (_Float16)a.y; h[2] = (_Float16)a.z; h[3] = (_Float16)a.w;
        h[4] = (_Float16)b.x; h[5] = (_Float16)b.y; h[6] = (_Float16)b.z; h[7] = (_Float16)b.w;
        const int s  = srow & (S_ - 1);
        const int bh = srow >> 11;
        size_t off = (size_t)bh * KBYTES_PER_HEAD + (size_t)(s >> 6) * 8192
                   + (s & 63) * 128 + ((gcol ^ (s & 7)) << 4);
        *(f16x8*)(ws + off) = h;
    } else {
        __shared__ _Float16 Vl[64][72];
        const int tile = blockIdx.x - (B_ * H_ * S_ * 8) / 256;  // bh*32 + t
        const int bh = tile >> 5, t = tile & 31;
        const float* vb = V + ((size_t)bh * S_ + t * 64) * D_;
        const int tid = threadIdx.x;
        #pragma unroll
        for (int it = 0; it < 2; ++it) {
            const int row = (tid >> 3) + it * 32;
            const int c8  = (tid & 7) * 8;
            const float4* p = (const float4*)(vb + row * D_ + c8);
            float4 a = p[0], b = p[1];
            f16x8 h;
            h[0] = (_Float16)a.x; h[1] = (_Float16)a.y; h[2] = (_Float16)a.z; h[3] = (_Float16)a.w;
            h[4] = (_Float16)b.x; h[5] = (_Float16)b.y; h[6] = (_Float16)b.z; h[7] = (_Float16)b.w;
            *(f16x8*)&Vl[row][c8] = h;
        }
        __syncthreads();
        char* out = ws + WS_V_OFF + (size_t)bh * KBYTES_PER_HEAD + t * 8192;
        #pragma unroll
        for (int it = 0; it < 2; ++it) {
            const int task = tid + it * 256;
            const int d = task >> 3, kg = task & 7;
            f16x8 h;
            #pragma unroll
            for (int j = 0; j < 8; ++j) h[j] = Vl[kg * 8 + j][d];
            *(f16x8*)(out + d * 128 + ((kg ^ (d & 7)) << 4)) = h;
        }
    }
}

// ---------------- main attention kernel
template<bool MASK>
__device__ __forceinline__ void compute_tile(
    const _Float16* __restrict__ SMb, _Float16 (*__restrict__ Plw)[72],
    const f16x8 aq[2], f32x4 accO[4], float& m_r, float& l_r,
    int g, int l15, int sx, int dq)
{
    const _Float16* Kb = SMb;
    const _Float16* Vb = SMb + 4096;

    // QK^T swapped: A = K rows, B = Q  ->  C[k = sub*16+g*4+r][q = l15]
    f32x4 accS[4];
    #pragma unroll
    for (int s = 0; s < 4; ++s) accS[s] = (f32x4){0.f, 0.f, 0.f, 0.f};
    #pragma unroll
    for (int sub = 0; sub < 4; ++sub) {
        if (MASK && (sub * 16 > dq + 15)) continue;      // wave-uniform fully-masked sub
        #pragma unroll
        for (int kc = 0; kc < 2; ++kc) {
            f16x8 ak = *(const f16x8*)(Kb + ((sub * 16 + l15) * 64 + (((kc * 4 + g) ^ sx) << 3)));
            accS[sub] = __builtin_amdgcn_mfma_f32_16x16x32_f16(ak, aq[kc], accS[sub], 0, 0, 0);
        }
    }

    // online softmax (exp2 domain); q-row = l15 is lane-local
    float ps[4][4];
    float mx = -1e30f;
    #pragma unroll
    for (int sub = 0; sub < 4; ++sub) {
        const bool fullmask = MASK && (sub * 16 > dq + 15);
        const bool diag     = MASK && !fullmask && (sub * 16 + 15 > dq);
        #pragma unroll
        for (int r = 0; r < 4; ++r) {
            float s = fullmask ? -1e30f : accS[sub][r];
            if (diag && (sub * 16 + g * 4 + r > dq + l15)) s = -1e30f;
            ps[sub][r] = s;
            mx = fmaxf(mx, s);
        }
    }
    mx = fmaxf(mx, __shfl_xor(mx, 16));
    mx = fmaxf(mx, __shfl_xor(mx, 32));
    const float mnew  = fmaxf(m_r, mx);
    const float alpha = __builtin_amdgcn_exp2f(m_r - mnew);
    float rs = 0.f;
    #pragma unroll
    for (int sub = 0; sub < 4; ++sub)
        #pragma unroll
        for (int r = 0; r < 4; ++r) {
            const float p = __builtin_amdgcn_exp2f(ps[sub][r] - mnew);
            ps[sub][r] = p;
            rs += p;
        }
    rs += __shfl_xor(rs, 16);
    rs += __shfl_xor(rs, 32);
    l_r = l_r * alpha + rs;
    m_r = mnew;

    // P -> LDS relayout (wave-local): row q=l15, col k
    #pragma unroll
    for (int sub = 0; sub < 4; ++sub) {
        f16x4 q4;
        q4[0] = (_Float16)ps[sub][0]; q4[1] = (_Float16)ps[sub][1];
        q4[2] = (_Float16)ps[sub][2]; q4[3] = (_Float16)ps[sub][3];
        *(f16x4*)&Plw[l15][sub * 16 + g * 4] = q4;
    }

    #pragma unroll
    for (int d = 0; d < 4; ++d)
        #pragma unroll
        for (int r = 0; r < 4; ++r) accO[d][r] *= alpha;   // alpha lane-uniform in q=l15

    asm volatile("s_waitcnt lgkmcnt(0)" ::: "memory");
    __builtin_amdgcn_sched_barrier(0);

    f16x8 pb[2];
    pb[0] = *(const f16x8*)&Plw[l15][g * 8];
    pb[1] = *(const f16x8*)&Plw[l15][32 + g * 8];

    // PV swapped: A = V^T rows (d), B = P^T cols (q) -> accO[dsub]: d = dsub*16+g*4+r, q = l15
    #pragma unroll
    for (int d = 0; d < 4; ++d)
        #pragma unroll
        for (int kc = 0; kc < 2; ++kc) {
            f16x8 av = *(const f16x8*)(Vb + ((d * 16 + l15) * 64 + (((kc * 4 + g) ^ sx) << 3)));
            accO[d] = __builtin_amdgcn_mfma_f32_16x16x32_f16(av, pb[kc], accO[d], 0, 0, 0);
        }
}

__global__ __launch_bounds__(512, 4) void attn_main(
    const float* __restrict__ Q, const char* __restrict__ ws, float* __restrict__ O)
{
    __shared__ _Float16 SM[2][8192];        // [buf][ K tile 0..4095 | V tile 4096..8191 ]
    __shared__ _Float16 Pl[NW][16][72];

    const int tid  = threadIdx.x;
    const int lane = tid & 63;
    const int w    = tid >> 6;              // wave 0..7
    const int g    = lane >> 4;
    const int l15  = lane & 15;
    const int sx   = l15 & 7;

    // 1-D grid: id = bh + 32*qi  ->  id%8 = bh%8 (head -> XCD affinity, K/V L2-resident);
    // qt reversed so heaviest blocks dispatch first.
    const int id    = blockIdx.x;
    const int bh    = id & 31;
    const int qt    = (S_ / BQ - 1) - (id >> 5);
    const int qbase = qt * BQ;

    const char* kbase = ws + (size_t)bh * KBYTES_PER_HEAD;
    const char* vbase = ws + WS_V_OFF + (size_t)bh * KBYTES_PER_HEAD;

    // hoist Q fragments, pre-scaled into exp2 domain
    f16x8 aq[2];
    {
        const float* qrow = Q + ((size_t)bh * S_ + qbase + w * 16 + l15) * D_;
        #pragma unroll
        for (int kc = 0; kc < 2; ++kc) {
            const float4* p = (const float4*)(qrow + kc * 32 + g * 8);
            float4 x0 = p[0], x1 = p[1];
            f16x8 h;
            h[0] = (_Float16)(x0.x * QSCALE); h[1] = (_Float16)(x0.y * QSCALE);
            h[2] = (_Float16)(x0.z * QSCALE); h[3] = (_Float16)(x0.w * QSCALE);
            h[4] = (_Float16)(x1.x * QSCALE); h[5] = (_Float16)(x1.y * QSCALE);
            h[6] = (_Float16)(x1.z * QSCALE); h[7] = (_Float16)(x1.w * QSCALE);
            aq[kc] = h;
        }
    }

    f32x4 accO[4];
    #pragma unroll
    for (int i = 0; i < 4; ++i) accO[i] = (f32x4){0.f, 0.f, 0.f, 0.f};
    float m_r = -1e30f, l_r = 0.f;

    const int nt = 2 * qt + 2;              // tiles; last two straddle the diagonal
    const int dqw = qbase + w * 16;         // wave q-row base

    // stage tile t: 16 x 1KB chunks, 2 per wave, linear LDS dest (pre-swizzled source)
    auto STAGE = [&](int t, int buf) {
        #pragma unroll
        for (int i = 0; i < 2; ++i) {
            const int c = w * 2 + i;
            const char* src = (c < 8 ? kbase + (size_t)t * 8192 + c * 1024
                                     : vbase + (size_t)t * 8192 + (c - 8) * 1024) + lane * 16;
            __builtin_amdgcn_global_load_lds((gu32*)src, (lu32*)&SM[buf][c * 512], 16, 0, 0);
        }
    };

    STAGE(0, 0);
    for (int t = 0; t < nt - 2; ++t) {      // fully-visible tiles
        STAGE(t + 1, (t + 1) & 1);
        asm volatile("s_waitcnt vmcnt(2)" ::: "memory");
        __builtin_amdgcn_s_barrier();
        compute_tile<false>(&SM[t & 1][0], Pl[w], aq, accO, m_r, l_r, g, l15, sx, 0);
        __builtin_amdgcn_s_barrier();
    }
    // t = nt-2 (diagonal for waves 0-3)
    STAGE(nt - 1, (nt - 1) & 1);
    asm volatile("s_waitcnt vmcnt(2)" ::: "memory");
    __builtin_amdgcn_s_barrier();
    compute_tile<true>(&SM[(nt - 2) & 1][0], Pl[w], aq, accO, m_r, l_r, g, l15, sx,
                       dqw - (nt - 2) * 64);
    __builtin_amdgcn_s_barrier();
    // t = nt-1 (diagonal for waves 4-7; fully masked for 0-3)
    asm volatile("s_waitcnt vmcnt(0)" ::: "memory");
    __builtin_amdgcn_s_barrier();
    compute_tile<true>(&SM[(nt - 1) & 1][0], Pl[w], aq, accO, m_r, l_r, g, l15, sx,
                       dqw - (nt - 1) * 64);

    // epilogue: O[q][d], float4 stores
    const float inv = 1.0f / l_r;
    float* orow = O + ((size_t)bh * S_ + qbase + w * 16 + l15) * D_;
    #pragma unroll
    for (int d = 0; d < 4; ++d) {
        f32x4 o = accO[d] * inv;
        *(f32x4*)&orow[d * 16 + g * 4] = o;
    }
}

extern "C" void kernel_launch(void* const* d_in, const int* in_sizes, int n_in,
                              void* d_out, int out_size, void* d_ws, size_t ws_size,
                              hipStream_t stream) {
    const float* q = (const float*)d_in[0];
    const float* k = (const float*)d_in[1];
    const float* v = (const float*)d_in[2];
    // d_in[3] (mask) intentionally never read — causality computed in-kernel
    float* o = (float*)d_out;
    char* ws = (char*)d_ws;

    if (ws_size < WS_NEED) return;

    const int kblocks = (B_ * H_ * S_ * 8) / 256;        // 1024
    const int vblocks = B_ * H_ * (S_ / 64);             // 1024
    prep_kv<<<kblocks + vblocks, 256, 0, stream>>>(k, v, ws);
    attn_main<<<(S_ / BQ) * B_ * H_, 512, 0, stream>>>(q, ws, o);
}

// Round 4
// 53.625 us; speedup vs baseline: 4.0486x; 1.0664x over previous
//
#include <hip/hip_runtime.h>

#define B_   2
#define H_   16
#define S_   2048
#define D_   64
#define BQ   128    // q rows per block (16 per wave, 8 waves)
#define BK   64
#define NW   8
// fold 1/sqrt(64) * log2(e) into Q so softmax works in exp2 domain
#define QSCALE 0.18033688011112042f
#define DEFER_THR 8.0f

typedef _Float16 f16x8 __attribute__((ext_vector_type(8)));
typedef _Float16 f16x4 __attribute__((ext_vector_type(4)));
typedef float    f32x4 __attribute__((ext_vector_type(4)));

typedef const unsigned int __attribute__((address_space(1))) gu32;
typedef unsigned int       __attribute__((address_space(3))) lu32;

#define KBYTES_PER_HEAD (S_ * 128)                       // 256 KB f16 per head per tensor
#define WS_V_OFF ((size_t)B_ * H_ * KBYTES_PER_HEAD)     // 8.4 MB
#define WS_NEED  (2 * WS_V_OFF)

// ---------------- fused prepass: K -> swizzled f16 tiles, V -> transposed swizzled f16 tiles
// K tile image: element (row,d) at byte  row*128 + (((d>>3) ^ (row&7))<<4) + (d&7)*2
// V tile image: element (d,k)  at byte  d*128   + (((k>>3) ^ (d&7))<<4)   + (k&7)*2
__global__ __launch_bounds__(256) void prep_kv(const float* __restrict__ K,
                                               const float* __restrict__ V,
                                               char* __restrict__ ws)
{
    if (blockIdx.x < (B_ * H_ * S_ * 8) / 256) {
        const int gidx = blockIdx.x * 256 + threadIdx.x;
        const int gcol = gidx & 7;
        const int srow = gidx >> 3;                      // bh*S + s
        const float4* src = (const float4*)(K + (size_t)srow * D_ + gcol * 8);
        float4 a = src[0], b = src[1];
        f16x8 h;
        h[0] = (_Float16)a.x; h[1] = (_Float16)a.y; h[2] = (_Float16)a.z; h[3] = (_Float16)a.w;
        h[4] = (_Float16)b.x; h[5] = (_Float16)b.y; h[6] = (_Float16)b.z; h[7] = (_Float16)b.w;
        const int s  = srow & (S_ - 1);
        const int bh = srow >> 11;
        size_t off = (size_t)bh * KBYTES_PER_HEAD + (size_t)(s >> 6) * 8192
                   + (s & 63) * 128 + ((gcol ^ (s & 7)) << 4);
        *(f16x8*)(ws + off) = h;
    } else {
        __shared__ _Float16 Vl[64][72];
        const int tile = blockIdx.x - (B_ * H_ * S_ * 8) / 256;  // bh*32 + t
        const int bh = tile >> 5, t = tile & 31;
        const float* vb = V + ((size_t)bh * S_ + t * 64) * D_;
        const int tid = threadIdx.x;
        #pragma unroll
        for (int it = 0; it < 2; ++it) {
            const int row = (tid >> 3) + it * 32;
            const int c8  = (tid & 7) * 8;
            const float4* p = (const float4*)(vb + row * D_ + c8);
            float4 a = p[0], b = p[1];
            f16x8 h;
            h[0] = (_Float16)a.x; h[1] = (_Float16)a.y; h[2] = (_Float16)a.z; h[3] = (_Float16)a.w;
            h[4] = (_Float16)b.x; h[5] = (_Float16)b.y; h[6] = (_Float16)b.z; h[7] = (_Float16)b.w;
            *(f16x8*)&Vl[row][c8] = h;
        }
        __syncthreads();
        char* out = ws + WS_V_OFF + (size_t)bh * KBYTES_PER_HEAD + t * 8192;
        #pragma unroll
        for (int it = 0; it < 2; ++it) {
            const int task = tid + it * 256;
            const int d = task >> 3, kg = task & 7;
            f16x8 h;
            #pragma unroll
            for (int j = 0; j < 8; ++j) h[j] = Vl[kg * 8 + j][d];
            *(f16x8*)(out + d * 128 + ((kg ^ (d & 7)) << 4)) = h;
        }
    }
}

// ---------------- main attention kernel
template<bool MASK>
__device__ __forceinline__ void compute_tile(
    const _Float16* __restrict__ SMb, _Float16 (*__restrict__ Plw)[72],
    const f16x8 aq[2], f32x4 accO[4], float& m_r, float& l_r,
    int g, int l15, int sx, int dq)
{
    const _Float16* Kb = SMb;
    const _Float16* Vb = SMb + 4096;

    // QK^T swapped: A = K rows, B = Q  ->  C[k = sub*16+g*4+r][q = l15]
    f32x4 accS[4];
    #pragma unroll
    for (int s = 0; s < 4; ++s) accS[s] = (f32x4){0.f, 0.f, 0.f, 0.f};
    __builtin_amdgcn_s_setprio(1);
    #pragma unroll
    for (int sub = 0; sub < 4; ++sub) {
        if (MASK && (sub * 16 > dq + 15)) continue;      // wave-uniform fully-masked sub
        #pragma unroll
        for (int kc = 0; kc < 2; ++kc) {
            f16x8 ak = *(const f16x8*)(Kb + ((sub * 16 + l15) * 64 + (((kc * 4 + g) ^ sx) << 3)));
            accS[sub] = __builtin_amdgcn_mfma_f32_16x16x32_f16(ak, aq[kc], accS[sub], 0, 0, 0);
        }
    }
    __builtin_amdgcn_s_setprio(0);

    // masked scores + per-lane local max (this lane's 16 k-values for q = l15)
    float ps[4][4];
    float pmax = -1e30f;
    #pragma unroll
    for (int sub = 0; sub < 4; ++sub) {
        const bool fullmask = MASK && (sub * 16 > dq + 15);
        const bool diag     = MASK && !fullmask && (sub * 16 + 15 > dq);
        #pragma unroll
        for (int r = 0; r < 4; ++r) {
            float s = fullmask ? -1e30f : accS[sub][r];
            if (diag && (sub * 16 + g * 4 + r > dq + l15)) s = -1e30f;
            ps[sub][r] = s;
            pmax = fmaxf(pmax, s);
        }
    }

    // defer-max (T13): rescale only when some lane's local max outgrows m_r + THR.
    // Branch is wave-uniform (ballot). Common case: no cross-lane ops at all.
    if (!__all(pmax <= m_r + DEFER_THR)) {
        float mx = pmax;
        mx = fmaxf(mx, __shfl_xor(mx, 16));
        mx = fmaxf(mx, __shfl_xor(mx, 32));
        const float mnew  = fmaxf(m_r, mx);               // row-uniform
        const float alpha = __builtin_amdgcn_exp2f(m_r - mnew);
        l_r *= alpha;
        #pragma unroll
        for (int d = 0; d < 4; ++d)
            #pragma unroll
            for (int r = 0; r < 4; ++r) accO[d][r] *= alpha;
        m_r = mnew;
    }

    // exp2 with (possibly stale-by-<=THR) m_r: values bounded by 2^THR = 256, f16-safe.
    #pragma unroll
    for (int sub = 0; sub < 4; ++sub)
        #pragma unroll
        for (int r = 0; r < 4; ++r)
            ps[sub][r] = __builtin_amdgcn_exp2f(ps[sub][r] - m_r);

    // P -> LDS relayout first (get ds_writes in flight early): row q=l15, col k
    #pragma unroll
    for (int sub = 0; sub < 4; ++sub) {
        f16x4 q4;
        q4[0] = (_Float16)ps[sub][0]; q4[1] = (_Float16)ps[sub][1];
        q4[2] = (_Float16)ps[sub][2]; q4[3] = (_Float16)ps[sub][3];
        *(f16x4*)&Plw[l15][sub * 16 + g * 4] = q4;
    }

    // per-lane partial row-sum; cross-lane reduce deferred to epilogue
    float rs = 0.f;
    #pragma unroll
    for (int sub = 0; sub < 4; ++sub)
        #pragma unroll
        for (int r = 0; r < 4; ++r) rs += ps[sub][r];
    l_r += rs;

    asm volatile("s_waitcnt lgkmcnt(0)" ::: "memory");
    __builtin_amdgcn_sched_barrier(0);

    f16x8 pb[2];
    pb[0] = *(const f16x8*)&Plw[l15][g * 8];
    pb[1] = *(const f16x8*)&Plw[l15][32 + g * 8];

    // PV swapped: A = V^T rows (d), B = P^T cols (q) -> accO[dsub]: d = dsub*16+g*4+r, q = l15
    __builtin_amdgcn_s_setprio(1);
    #pragma unroll
    for (int d = 0; d < 4; ++d)
        #pragma unroll
        for (int kc = 0; kc < 2; ++kc) {
            f16x8 av = *(const f16x8*)(Vb + ((d * 16 + l15) * 64 + (((kc * 4 + g) ^ sx) << 3)));
            accO[d] = __builtin_amdgcn_mfma_f32_16x16x32_f16(av, pb[kc], accO[d], 0, 0, 0);
        }
    __builtin_amdgcn_s_setprio(0);
}

__global__ __launch_bounds__(512, 4) void attn_main(
    const float* __restrict__ Q, const char* __restrict__ ws, float* __restrict__ O)
{
    __shared__ _Float16 SM[2][8192];        // [buf][ K tile 0..4095 | V tile 4096..8191 ]
    __shared__ _Float16 Pl[NW][16][72];

    const int tid  = threadIdx.x;
    const int lane = tid & 63;
    const int w    = tid >> 6;              // wave 0..7
    const int g    = lane >> 4;
    const int l15  = lane & 15;
    const int sx   = l15 & 7;

    // 1-D grid: id = bh + 32*qi  ->  id%8 = bh%8 (head -> XCD affinity, K/V L2-resident);
    // qt reversed so heaviest blocks dispatch first.
    const int id    = blockIdx.x;
    const int bh    = id & 31;
    const int qt    = (S_ / BQ - 1) - (id >> 5);
    const int qbase = qt * BQ;

    const char* kbase = ws + (size_t)bh * KBYTES_PER_HEAD;
    const char* vbase = ws + WS_V_OFF + (size_t)bh * KBYTES_PER_HEAD;

    // hoist Q fragments, pre-scaled into exp2 domain
    f16x8 aq[2];
    {
        const float* qrow = Q + ((size_t)bh * S_ + qbase + w * 16 + l15) * D_;
        #pragma unroll
        for (int kc = 0; kc < 2; ++kc) {
            const float4* p = (const float4*)(qrow + kc * 32 + g * 8);
            float4 x0 = p[0], x1 = p[1];
            f16x8 h;
            h[0] = (_Float16)(x0.x * QSCALE); h[1] = (_Float16)(x0.y * QSCALE);
            h[2] = (_Float16)(x0.z * QSCALE); h[3] = (_Float16)(x0.w * QSCALE);
            h[4] = (_Float16)(x1.x * QSCALE); h[5] = (_Float16)(x1.y * QSCALE);
            h[6] = (_Float16)(x1.z * QSCALE); h[7] = (_Float16)(x1.w * QSCALE);
            aq[kc] = h;
        }
    }

    f32x4 accO[4];
    #pragma unroll
    for (int i = 0; i < 4; ++i) accO[i] = (f32x4){0.f, 0.f, 0.f, 0.f};
    float m_r = -1e30f, l_r = 0.f;

    const int nt = 2 * qt + 2;              // tiles; last two straddle the diagonal
    const int dqw = qbase + w * 16;         // wave q-row base

    // stage tile t: 16 x 1KB chunks, 2 per wave, linear LDS dest (pre-swizzled source)
    auto STAGE = [&](int t, int buf) {
        #pragma unroll
        for (int i = 0; i < 2; ++i) {
            const int c = w * 2 + i;
            const char* src = (c < 8 ? kbase + (size_t)t * 8192 + c * 1024
                                     : vbase + (size_t)t * 8192 + (c - 8) * 1024) + lane * 16;
            __builtin_amdgcn_global_load_lds((gu32*)src, (lu32*)&SM[buf][c * 512], 16, 0, 0);
        }
    };

    STAGE(0, 0);
    for (int t = 0; t < nt - 2; ++t) {      // fully-visible tiles
        STAGE(t + 1, (t + 1) & 1);
        asm volatile("s_waitcnt vmcnt(2)" ::: "memory");
        __builtin_amdgcn_s_barrier();
        compute_tile<false>(&SM[t & 1][0], Pl[w], aq, accO, m_r, l_r, g, l15, sx, 0);
        __builtin_amdgcn_s_barrier();
    }
    // t = nt-2 (diagonal for waves 0-3)
    STAGE(nt - 1, (nt - 1) & 1);
    asm volatile("s_waitcnt vmcnt(2)" ::: "memory");
    __builtin_amdgcn_s_barrier();
    compute_tile<true>(&SM[(nt - 2) & 1][0], Pl[w], aq, accO, m_r, l_r, g, l15, sx,
                       dqw - (nt - 2) * 64);
    __builtin_amdgcn_s_barrier();
    // t = nt-1 (diagonal for waves 4-7; fully masked for 0-3)
    asm volatile("s_waitcnt vmcnt(0)" ::: "memory");
    __builtin_amdgcn_s_barrier();
    compute_tile<true>(&SM[(nt - 1) & 1][0], Pl[w], aq, accO, m_r, l_r, g, l15, sx,
                       dqw - (nt - 1) * 64);

    // epilogue: complete the deferred row-sum reduce (once per kernel, not per tile)
    float l = l_r;
    l += __shfl_xor(l, 16);
    l += __shfl_xor(l, 32);
    const float inv = 1.0f / l;
    float* orow = O + ((size_t)bh * S_ + qbase + w * 16 + l15) * D_;
    #pragma unroll
    for (int d = 0; d < 4; ++d) {
        f32x4 o = accO[d] * inv;
        *(f32x4*)&orow[d * 16 + g * 4] = o;
    }
}

extern "C" void kernel_launch(void* const* d_in, const int* in_sizes, int n_in,
                              void* d_out, int out_size, void* d_ws, size_t ws_size,
                              hipStream_t stream) {
    const float* q = (const float*)d_in[0];
    const float* k = (const float*)d_in[1];
    const float* v = (const float*)d_in[2];
    // d_in[3] (mask) intentionally never read — causality computed in-kernel
    float* o = (float*)d_out;
    char* ws = (char*)d_ws;

    if (ws_size < WS_NEED) return;

    const int kblocks = (B_ * H_ * S_ * 8) / 256;        // 1024
    const int vblocks = B_ * H_ * (S_ / 64);             // 1024
    prep_kv<<<kblocks + vblocks, 256, 0, stream>>>(k, v, ws);
    attn_main<<<(S_ / BQ) * B_ * H_, 512, 0, stream>>>(q, ws, o);
}